// Round 1
// 501.629 us; speedup vs baseline: 1.0021x; 1.0021x over previous
//
#include <hip/hip_runtime.h>
#include <stdint.h>
#include <stddef.h>

typedef __attribute__((ext_vector_type(4))) int i32x4;

#define BM 128
#define BN 128
#define BK 64

// ---------------- async global -> LDS (16B per lane) ----------------
__device__ __forceinline__ void gload_lds16(const void* g, void* l) {
    __builtin_amdgcn_global_load_lds(
        (const __attribute__((address_space(1))) void*)g,
        (__attribute__((address_space(3))) void*)l,
        16, 0, 0);
}

// ---------------- wave-wide butterfly reductions (all lanes get result) ----------------
__device__ __forceinline__ float waveAllMaxF(float v) {
#pragma unroll
    for (int m = 32; m > 0; m >>= 1) v = fmaxf(v, __shfl_xor(v, m, 64));
    return v;
}
__device__ __forceinline__ float waveAllMinF(float v) {
#pragma unroll
    for (int m = 32; m > 0; m >>= 1) v = fminf(v, __shfl_xor(v, m, 64));
    return v;
}
__device__ __forceinline__ int waveAllSumI(int v) {
#pragma unroll
    for (int m = 32; m > 0; m >>= 1) v += __shfl_xor(v, m, 64);
    return v;
}

// ---------------- weight quantization: row-wise symmetric int8 ----------------
// ONE WAVE per row. K==4096 fast path: the whole 16KB row lives in 64 VGPRs/lane
// (16 float4 each), loaded with 16 independent coalesced dwordx4 loads (full ILP),
// single pass, no LDS, no __syncthreads. Writes Wq (int8), rscale, rsum.
__global__ void __launch_bounds__(256) wquant_kernel(
    const float* __restrict__ W, int8_t* __restrict__ Wq,
    float* __restrict__ rscale, int* __restrict__ rsum, int K) {
    const int n = blockIdx.x * 4 + (threadIdx.x >> 6);
    const int lane = threadIdx.x & 63;
    const float4* row = (const float4*)(W + (size_t)n * K);
    int* out = (int*)(Wq + (size_t)n * K);

    if (K == 4096) {
        float4 v[16];
#pragma unroll
        for (int j = 0; j < 16; ++j) v[j] = row[lane + (j << 6)];

        float amax = 0.f;
#pragma unroll
        for (int j = 0; j < 16; ++j) {
            amax = fmaxf(amax, fmaxf(fmaxf(fabsf(v[j].x), fabsf(v[j].y)),
                                     fmaxf(fabsf(v[j].z), fabsf(v[j].w))));
        }
        amax = waveAllMaxF(amax);
        const float scale = (amax > 0.f) ? (amax / 127.0f) : 1.0f;

        int lsum = 0;
#pragma unroll
        for (int j = 0; j < 16; ++j) {
            int q0 = (int)fminf(fmaxf(rintf(v[j].x / scale), -127.f), 127.f);
            int q1 = (int)fminf(fmaxf(rintf(v[j].y / scale), -127.f), 127.f);
            int q2 = (int)fminf(fmaxf(rintf(v[j].z / scale), -127.f), 127.f);
            int q3 = (int)fminf(fmaxf(rintf(v[j].w / scale), -127.f), 127.f);
            lsum += q0 + q1 + q2 + q3;
            out[lane + (j << 6)] =
                (q0 & 255) | ((q1 & 255) << 8) | ((q2 & 255) << 16) | ((q3 & 255) << 24);
        }
        lsum = waveAllSumI(lsum);
        if (lane == 0) { rsum[n] = lsum; rscale[n] = scale; }
    } else {
        // generic fallback: per-wave two-pass
        const int K4 = K >> 2;
        float amax = 0.f;
        for (int i = lane; i < K4; i += 64) {
            float4 f = row[i];
            amax = fmaxf(amax, fmaxf(fmaxf(fabsf(f.x), fabsf(f.y)),
                                     fmaxf(fabsf(f.z), fabsf(f.w))));
        }
        amax = waveAllMaxF(amax);
        const float scale = (amax > 0.f) ? (amax / 127.0f) : 1.0f;
        int lsum = 0;
        for (int i = lane; i < K4; i += 64) {
            float4 f = row[i];
            int q0 = (int)fminf(fmaxf(rintf(f.x / scale), -127.f), 127.f);
            int q1 = (int)fminf(fmaxf(rintf(f.y / scale), -127.f), 127.f);
            int q2 = (int)fminf(fmaxf(rintf(f.z / scale), -127.f), 127.f);
            int q3 = (int)fminf(fmaxf(rintf(f.w / scale), -127.f), 127.f);
            lsum += q0 + q1 + q2 + q3;
            out[i] = (q0 & 255) | ((q1 & 255) << 8) | ((q2 & 255) << 16) | ((q3 & 255) << 24);
        }
        lsum = waveAllSumI(lsum);
        if (lane == 0) { rsum[n] = lsum; rscale[n] = scale; }
    }
}

// ---------------- activation quantization: per-token asymmetric uint8 ----------------
// ONE WAVE per token, same register-resident single-pass structure.
// Stores (Xq - 128) as signed int8; azp[m] = 128 - zp.
__global__ void __launch_bounds__(256) aquant_kernel(
    const float* __restrict__ X, int8_t* __restrict__ Xq,
    float* __restrict__ cscale, int* __restrict__ azp, int K) {
    const int m = blockIdx.x * 4 + (threadIdx.x >> 6);
    const int lane = threadIdx.x & 63;
    const float4* row = (const float4*)(X + (size_t)m * K);
    int* out = (int*)(Xq + (size_t)m * K);

    if (K == 4096) {
        float4 v[16];
#pragma unroll
        for (int j = 0; j < 16; ++j) v[j] = row[lane + (j << 6)];

        float vmin = 3.402823466e38f, vmax = -3.402823466e38f;
#pragma unroll
        for (int j = 0; j < 16; ++j) {
            vmin = fminf(vmin, fminf(fminf(v[j].x, v[j].y), fminf(v[j].z, v[j].w)));
            vmax = fmaxf(vmax, fmaxf(fmaxf(v[j].x, v[j].y), fmaxf(v[j].z, v[j].w)));
        }
        vmin = waveAllMinF(vmin);
        vmax = waveAllMaxF(vmax);

        const float rng = vmax - vmin;
        const float scale = (rng > 0.f) ? (rng / 255.0f) : 1.0f;
        const float zp = rintf(-vmin / scale);

#pragma unroll
        for (int j = 0; j < 16; ++j) {
            int q0 = (int)fminf(fmaxf(rintf(v[j].x / scale) + zp, 0.f), 255.f) - 128;
            int q1 = (int)fminf(fmaxf(rintf(v[j].y / scale) + zp, 0.f), 255.f) - 128;
            int q2 = (int)fminf(fmaxf(rintf(v[j].z / scale) + zp, 0.f), 255.f) - 128;
            int q3 = (int)fminf(fmaxf(rintf(v[j].w / scale) + zp, 0.f), 255.f) - 128;
            out[lane + (j << 6)] =
                (q0 & 255) | ((q1 & 255) << 8) | ((q2 & 255) << 16) | ((q3 & 255) << 24);
        }
        if (lane == 0) { cscale[m] = scale; azp[m] = 128 - (int)zp; }
    } else {
        // generic fallback: per-wave two-pass
        const int K4 = K >> 2;
        float vmin = 3.402823466e38f, vmax = -3.402823466e38f;
        for (int i = lane; i < K4; i += 64) {
            float4 f = row[i];
            vmin = fminf(vmin, fminf(fminf(f.x, f.y), fminf(f.z, f.w)));
            vmax = fmaxf(vmax, fmaxf(fmaxf(f.x, f.y), fmaxf(f.z, f.w)));
        }
        vmin = waveAllMinF(vmin);
        vmax = waveAllMaxF(vmax);
        const float rng = vmax - vmin;
        const float scale = (rng > 0.f) ? (rng / 255.0f) : 1.0f;
        const float zp = rintf(-vmin / scale);
        for (int i = lane; i < K4; i += 64) {
            float4 f = row[i];
            int q0 = (int)fminf(fmaxf(rintf(f.x / scale) + zp, 0.f), 255.f) - 128;
            int q1 = (int)fminf(fmaxf(rintf(f.y / scale) + zp, 0.f), 255.f) - 128;
            int q2 = (int)fminf(fmaxf(rintf(f.z / scale) + zp, 0.f), 255.f) - 128;
            int q3 = (int)fminf(fmaxf(rintf(f.w / scale) + zp, 0.f), 255.f) - 128;
            out[i] = (q0 & 255) | ((q1 & 255) << 8) | ((q2 & 255) << 16) | ((q3 & 255) << 24);
        }
        if (lane == 0) { cscale[m] = scale; azp[m] = 128 - (int)zp; }
    }
}

// ---------------- int8 GEMM (A: [M,K] i8, B: [N,K] i8) + dequant epilogue ----------------
// (unchanged this round — next round: 256^2 8-phase counted-vmcnt port)
// Y[m,n] = (dot_i8(A[m],B[n]) + azp[m]*rsum[n]) * cs[m]*rs[n] + bias[n]
__global__ void __launch_bounds__(256) gemm_i8_kernel(
    const int8_t* __restrict__ A, const int8_t* __restrict__ B,
    float* __restrict__ Y,
    const float* __restrict__ cs, const int* __restrict__ azp,
    const float* __restrict__ rs, const int* __restrict__ rsum,
    const float* __restrict__ bias, int M, int N, int K) {
    __shared__ int8_t As[BM * BK];  // 8 KB
    __shared__ int8_t Bs[BN * BK];  // 8 KB

    const int tid = threadIdx.x;
    const int lane = tid & 63;
    const int wave = tid >> 6;
    const int wm = wave & 1;
    const int wn = wave >> 1;
    const int quad = lane >> 4;
    const int lr = lane & 15;

    const int bm = blockIdx.x * BM;
    const int bn = blockIdx.y * BN;

    const int8_t* Ag = A + (size_t)bm * K;
    const int8_t* Bg = B + (size_t)bn * K;

    // staging: thread t loads 16B at row t/4, byte col (t&3)*16; LDS offset = tid*16
    const int srow = tid >> 2;
    const int scol = (tid & 3) << 4;

    i32x4 acc[4][4] = {};

    for (int k0 = 0; k0 < K; k0 += BK) {
        gload_lds16(Ag + (size_t)srow * K + (k0 + scol), &As[srow * BK + scol]);
        gload_lds16(Ag + (size_t)(srow + 64) * K + (k0 + scol), &As[(srow + 64) * BK + scol]);
        gload_lds16(Bg + (size_t)srow * K + (k0 + scol), &Bs[srow * BK + scol]);
        gload_lds16(Bg + (size_t)(srow + 64) * K + (k0 + scol), &Bs[(srow + 64) * BK + scol]);
        __syncthreads();  // compiler drains vmcnt before s_barrier -> LDS valid

        i32x4 af[4], bf[4];
#pragma unroll
        for (int i = 0; i < 4; ++i)
            af[i] = *(const i32x4*)&As[(wm * 64 + i * 16 + lr) * BK + quad * 16];
#pragma unroll
        for (int j = 0; j < 4; ++j)
            bf[j] = *(const i32x4*)&Bs[(wn * 64 + j * 16 + lr) * BK + quad * 16];

#pragma unroll
        for (int i = 0; i < 4; ++i)
#pragma unroll
            for (int j = 0; j < 4; ++j)
                acc[i][j] = __builtin_amdgcn_mfma_i32_16x16x64_i8(af[i], bf[j], acc[i][j], 0, 0, 0);

        __syncthreads();  // protect LDS from next iteration's staging
    }

    // epilogue: C/D layout col = lane&15 (n side), row = quad*4 + reg (m side)
#pragma unroll
    for (int i = 0; i < 4; ++i) {
        const int mb = bm + wm * 64 + i * 16 + quad * 4;
#pragma unroll
        for (int r = 0; r < 4; ++r) {
            const int m = mb + r;
            const float csm = cs[m];
            const int az = azp[m];
            float* yrow = Y + (size_t)m * N;
#pragma unroll
            for (int j = 0; j < 4; ++j) {
                const int n = bn + wn * 64 + j * 16 + lr;
                const int tot = acc[i][j][r] + az * rsum[n];
                yrow[n] = fmaf((float)tot, csm * rs[n], bias[n]);
            }
        }
    }
}

// ---------------- launch ----------------
extern "C" void kernel_launch(void* const* d_in, const int* in_sizes, int n_in,
                              void* d_out, int out_size, void* d_ws, size_t ws_size,
                              hipStream_t stream) {
    const float* x = (const float*)d_in[0];
    const float* w = (const float*)d_in[1];
    const float* bias = (const float*)d_in[2];
    float* y = (float*)d_out;

    const int N = in_sizes[2];            // 4096
    const int K = in_sizes[1] / N;        // 4096
    const int M = in_sizes[0] / K;        // 8192

    uint8_t* ws = (uint8_t*)d_ws;
    int8_t* Wq = (int8_t*)ws;                                  // N*K   int8
    int8_t* Xq = (int8_t*)(ws + (size_t)N * K);                // M*K   int8
    uint8_t* p = ws + (size_t)N * K + (size_t)M * K;
    p = (uint8_t*)(((uintptr_t)p + 255) & ~(uintptr_t)255);
    float* rscale = (float*)p;  p += (size_t)N * sizeof(float);
    int*   rsum   = (int*)p;    p += (size_t)N * sizeof(int);
    float* cscale = (float*)p;  p += (size_t)M * sizeof(float);
    int*   azp    = (int*)p;    p += (size_t)M * sizeof(int);

    wquant_kernel<<<N / 4, 256, 0, stream>>>(w, Wq, rscale, rsum, K);
    aquant_kernel<<<M / 4, 256, 0, stream>>>(x, Xq, cscale, azp, K);

    dim3 grid(M / BM, N / BN);
    gemm_i8_kernel<<<grid, 256, 0, stream>>>(Xq, Wq, y, cscale, azp,
                                             rscale, rsum, bias, M, N, K);
}

// Round 2
// 407.451 us; speedup vs baseline: 1.2337x; 1.2311x over previous
//
#include <hip/hip_runtime.h>
#include <stdint.h>
#include <stddef.h>

typedef __attribute__((ext_vector_type(4))) int i32x4;

// ---------------- async global -> LDS (16B per lane) ----------------
__device__ __forceinline__ void gload_lds16(const void* g, void* l) {
    __builtin_amdgcn_global_load_lds(
        (const __attribute__((address_space(1))) void*)g,
        (__attribute__((address_space(3))) void*)l,
        16, 0, 0);
}

// ---------------- wave-wide butterfly reductions (all lanes get result) ----------------
__device__ __forceinline__ float waveAllMaxF(float v) {
#pragma unroll
    for (int m = 32; m > 0; m >>= 1) v = fmaxf(v, __shfl_xor(v, m, 64));
    return v;
}
__device__ __forceinline__ float waveAllMinF(float v) {
#pragma unroll
    for (int m = 32; m > 0; m >>= 1) v = fminf(v, __shfl_xor(v, m, 64));
    return v;
}
__device__ __forceinline__ int waveAllSumI(int v) {
#pragma unroll
    for (int m = 32; m > 0; m >>= 1) v += __shfl_xor(v, m, 64);
    return v;
}

// ---------------- weight quantization: row-wise symmetric int8 ----------------
// ONE WAVE per row, row register-resident, single pass, no LDS/barriers.
__global__ void __launch_bounds__(256) wquant_kernel(
    const float* __restrict__ W, int8_t* __restrict__ Wq,
    float* __restrict__ rscale, int* __restrict__ rsum, int K) {
    const int n = blockIdx.x * 4 + (threadIdx.x >> 6);
    const int lane = threadIdx.x & 63;
    const float4* row = (const float4*)(W + (size_t)n * K);
    int* out = (int*)(Wq + (size_t)n * K);

    if (K == 4096) {
        float4 v[16];
#pragma unroll
        for (int j = 0; j < 16; ++j) v[j] = row[lane + (j << 6)];

        float amax = 0.f;
#pragma unroll
        for (int j = 0; j < 16; ++j) {
            amax = fmaxf(amax, fmaxf(fmaxf(fabsf(v[j].x), fabsf(v[j].y)),
                                     fmaxf(fabsf(v[j].z), fabsf(v[j].w))));
        }
        amax = waveAllMaxF(amax);
        const float scale = (amax > 0.f) ? (amax / 127.0f) : 1.0f;

        int lsum = 0;
#pragma unroll
        for (int j = 0; j < 16; ++j) {
            int q0 = (int)fminf(fmaxf(rintf(v[j].x / scale), -127.f), 127.f);
            int q1 = (int)fminf(fmaxf(rintf(v[j].y / scale), -127.f), 127.f);
            int q2 = (int)fminf(fmaxf(rintf(v[j].z / scale), -127.f), 127.f);
            int q3 = (int)fminf(fmaxf(rintf(v[j].w / scale), -127.f), 127.f);
            lsum += q0 + q1 + q2 + q3;
            out[lane + (j << 6)] =
                (q0 & 255) | ((q1 & 255) << 8) | ((q2 & 255) << 16) | ((q3 & 255) << 24);
        }
        lsum = waveAllSumI(lsum);
        if (lane == 0) { rsum[n] = lsum; rscale[n] = scale; }
    } else {
        const int K4 = K >> 2;
        float amax = 0.f;
        for (int i = lane; i < K4; i += 64) {
            float4 f = row[i];
            amax = fmaxf(amax, fmaxf(fmaxf(fabsf(f.x), fabsf(f.y)),
                                     fmaxf(fabsf(f.z), fabsf(f.w))));
        }
        amax = waveAllMaxF(amax);
        const float scale = (amax > 0.f) ? (amax / 127.0f) : 1.0f;
        int lsum = 0;
        for (int i = lane; i < K4; i += 64) {
            float4 f = row[i];
            int q0 = (int)fminf(fmaxf(rintf(f.x / scale), -127.f), 127.f);
            int q1 = (int)fminf(fmaxf(rintf(f.y / scale), -127.f), 127.f);
            int q2 = (int)fminf(fmaxf(rintf(f.z / scale), -127.f), 127.f);
            int q3 = (int)fminf(fmaxf(rintf(f.w / scale), -127.f), 127.f);
            lsum += q0 + q1 + q2 + q3;
            out[i] = (q0 & 255) | ((q1 & 255) << 8) | ((q2 & 255) << 16) | ((q3 & 255) << 24);
        }
        lsum = waveAllSumI(lsum);
        if (lane == 0) { rsum[n] = lsum; rscale[n] = scale; }
    }
}

// ---------------- activation quantization: per-token asymmetric uint8 ----------------
__global__ void __launch_bounds__(256) aquant_kernel(
    const float* __restrict__ X, int8_t* __restrict__ Xq,
    float* __restrict__ cscale, int* __restrict__ azp, int K) {
    const int m = blockIdx.x * 4 + (threadIdx.x >> 6);
    const int lane = threadIdx.x & 63;
    const float4* row = (const float4*)(X + (size_t)m * K);
    int* out = (int*)(Xq + (size_t)m * K);

    if (K == 4096) {
        float4 v[16];
#pragma unroll
        for (int j = 0; j < 16; ++j) v[j] = row[lane + (j << 6)];

        float vmin = 3.402823466e38f, vmax = -3.402823466e38f;
#pragma unroll
        for (int j = 0; j < 16; ++j) {
            vmin = fminf(vmin, fminf(fminf(v[j].x, v[j].y), fminf(v[j].z, v[j].w)));
            vmax = fmaxf(vmax, fmaxf(fmaxf(v[j].x, v[j].y), fmaxf(v[j].z, v[j].w)));
        }
        vmin = waveAllMinF(vmin);
        vmax = waveAllMaxF(vmax);

        const float rng = vmax - vmin;
        const float scale = (rng > 0.f) ? (rng / 255.0f) : 1.0f;
        const float zp = rintf(-vmin / scale);

#pragma unroll
        for (int j = 0; j < 16; ++j) {
            int q0 = (int)fminf(fmaxf(rintf(v[j].x / scale) + zp, 0.f), 255.f) - 128;
            int q1 = (int)fminf(fmaxf(rintf(v[j].y / scale) + zp, 0.f), 255.f) - 128;
            int q2 = (int)fminf(fmaxf(rintf(v[j].z / scale) + zp, 0.f), 255.f) - 128;
            int q3 = (int)fminf(fmaxf(rintf(v[j].w / scale) + zp, 0.f), 255.f) - 128;
            out[lane + (j << 6)] =
                (q0 & 255) | ((q1 & 255) << 8) | ((q2 & 255) << 16) | ((q3 & 255) << 24);
        }
        if (lane == 0) { cscale[m] = scale; azp[m] = 128 - (int)zp; }
    } else {
        const int K4 = K >> 2;
        float vmin = 3.402823466e38f, vmax = -3.402823466e38f;
        for (int i = lane; i < K4; i += 64) {
            float4 f = row[i];
            vmin = fminf(vmin, fminf(fminf(f.x, f.y), fminf(f.z, f.w)));
            vmax = fmaxf(vmax, fmaxf(fmaxf(f.x, f.y), fmaxf(f.z, f.w)));
        }
        vmin = waveAllMinF(vmin);
        vmax = waveAllMaxF(vmax);
        const float rng = vmax - vmin;
        const float scale = (rng > 0.f) ? (rng / 255.0f) : 1.0f;
        const float zp = rintf(-vmin / scale);
        for (int i = lane; i < K4; i += 64) {
            float4 f = row[i];
            int q0 = (int)fminf(fmaxf(rintf(f.x / scale) + zp, 0.f), 255.f) - 128;
            int q1 = (int)fminf(fmaxf(rintf(f.y / scale) + zp, 0.f), 255.f) - 128;
            int q2 = (int)fminf(fmaxf(rintf(f.z / scale) + zp, 0.f), 255.f) - 128;
            int q3 = (int)fminf(fmaxf(rintf(f.w / scale) + zp, 0.f), 255.f) - 128;
            out[i] = (q0 & 255) | ((q1 & 255) << 8) | ((q2 & 255) << 16) | ((q3 & 255) << 24);
        }
        if (lane == 0) { cscale[m] = scale; azp[m] = 128 - (int)zp; }
    }
}

// ---------------- int8 GEMM: 256x256 tile, 8 waves, double-buffered prefetch ----------------
// A: [M,K] i8 (Xq), B: [N,K] i8 (Wq).
// Y[m,n] = (dot_i8(A[m],B[n]) + azp[m]*rsum[n]) * cs[m]*rs[n] + bias[n]
//
// Geometry: BM=BN=256, BK=128 bytes, 512 threads = 8 waves (2 M-waves x 4 N-waves),
// per-wave output 128x64 -> acc[8][4] of 16x16 MFMA tiles, 64 MFMA per K-tile per wave.
// LDS: 2 buffers x (A 32KB + B 32KB) = 128 KB (dynamic).
// Schedule (T3 minimum 2-phase): stage tile t+1 FIRST, compute tile t, one barrier.
// LDS layout XOR-swizzled (slot ^= row&7, 16B slots) on BOTH stage-source and read
// (rule #21: global_load_lds writes linearly, so the source carries the involution).
__global__ void __launch_bounds__(512, 2) gemm_i8_kernel(
    const int8_t* __restrict__ A, const int8_t* __restrict__ B,
    float* __restrict__ Y,
    const float* __restrict__ cs, const int* __restrict__ azp,
    const float* __restrict__ rs, const int* __restrict__ rsum,
    const float* __restrict__ bias, int M, int N, int K) {
    extern __shared__ int8_t smem[];  // [2][A:32KB | B:32KB]

    const int tid = threadIdx.x;
    const int lane = tid & 63;
    const int wave = tid >> 6;
    const int wm = wave >> 2;   // 0..1  (M side, 128 rows each)
    const int wn = wave & 3;    // 0..3  (N side, 64 cols each)
    const int quad = lane >> 4; // 0..3
    const int lr = lane & 15;

    // ---- XCD-aware bijective block swizzle (consecutive work ids share the B panel) ----
    const int nwg = gridDim.x * gridDim.y;
    int wid = blockIdx.y * gridDim.x + blockIdx.x;
    if ((nwg & 7) == 0) wid = (wid & 7) * (nwg >> 3) + (wid >> 3);
    const int bm = (wid % gridDim.x) * 256;
    const int bn = (wid / gridDim.x) * 256;

    const int8_t* Ag = A + (size_t)bm * K;
    const int8_t* Bg = B + (size_t)bn * K;

    // ---- staging map: thread t covers LDS linear slot (row = q*64 + t/8, slot = t&7) ----
    const int sr = tid >> 3;                  // 0..63 row-within-sweep
    const int sc = tid & 7;                   // 16B slot
    const int csrc = (sc ^ (sr & 7)) << 4;    // swizzled source byte column

    i32x4 acc[8][4] = {};

    const int NT = K >> 7;  // K-tiles of 128 bytes

    // prologue: stage tile 0 into buffer 0
    {
        int8_t* dA = smem;
        int8_t* dB = smem + 32768;
#pragma unroll
        for (int q = 0; q < 4; ++q) {
            const int r = q * 64 + sr;
            gload_lds16(Ag + (size_t)r * K + csrc, dA + r * 128 + (sc << 4));
            gload_lds16(Bg + (size_t)r * K + csrc, dB + r * 128 + (sc << 4));
        }
    }
    __syncthreads();  // vmcnt(0) drain + barrier

    int buf = 0;
    for (int t = 0; t < NT; ++t) {
        // 1) issue next tile's staging first (overlaps with this tile's compute)
        if (t + 1 < NT) {
            const int k0 = (t + 1) << 7;
            int8_t* dA = smem + (buf ^ 1) * 65536;
            int8_t* dB = dA + 32768;
#pragma unroll
            for (int q = 0; q < 4; ++q) {
                const int r = q * 64 + sr;
                gload_lds16(Ag + (size_t)r * K + (k0 + csrc), dA + r * 128 + (sc << 4));
                gload_lds16(Bg + (size_t)r * K + (k0 + csrc), dB + r * 128 + (sc << 4));
            }
        }

        // 2) compute current tile
        const int8_t* Ab = smem + buf * 65536;
        const int8_t* Bb = Ab + 32768;
        const int axor = lr & 7;  // (row & 7) for all fragment rows (row ≡ lr mod 8)
#pragma unroll
        for (int kk = 0; kk < 2; ++kk) {
            i32x4 af[8], bf[4];
#pragma unroll
            for (int i = 0; i < 8; ++i) {
                const int row = wm * 128 + i * 16 + lr;
                const int slot = ((kk << 2) | quad) ^ axor;
                af[i] = *(const i32x4*)&Ab[row * 128 + (slot << 4)];
            }
#pragma unroll
            for (int j = 0; j < 4; ++j) {
                const int row = wn * 64 + j * 16 + lr;
                const int slot = ((kk << 2) | quad) ^ axor;
                bf[j] = *(const i32x4*)&Bb[row * 128 + (slot << 4)];
            }
#pragma unroll
            for (int i = 0; i < 8; ++i)
#pragma unroll
                for (int j = 0; j < 4; ++j)
                    acc[i][j] = __builtin_amdgcn_mfma_i32_16x16x64_i8(af[i], bf[j], acc[i][j], 0, 0, 0);
        }

        // 3) one barrier per tile: drains vmcnt (next tile staged) + lgkmcnt (reads done)
        __syncthreads();
        buf ^= 1;
    }

    // epilogue: C/D layout col = lane&15 (n side), row = quad*4 + reg (m side)
#pragma unroll
    for (int i = 0; i < 8; ++i) {
        const int mb = bm + wm * 128 + i * 16 + quad * 4;
#pragma unroll
        for (int r = 0; r < 4; ++r) {
            const int m = mb + r;
            const float csm = cs[m];
            const int az = azp[m];
            float* yrow = Y + (size_t)m * N;
#pragma unroll
            for (int j = 0; j < 4; ++j) {
                const int n = bn + wn * 64 + j * 16 + lr;
                const int tot = acc[i][j][r] + az * rsum[n];
                yrow[n] = fmaf((float)tot, csm * rs[n], bias[n]);
            }
        }
    }
}

// ---------------- launch ----------------
extern "C" void kernel_launch(void* const* d_in, const int* in_sizes, int n_in,
                              void* d_out, int out_size, void* d_ws, size_t ws_size,
                              hipStream_t stream) {
    const float* x = (const float*)d_in[0];
    const float* w = (const float*)d_in[1];
    const float* bias = (const float*)d_in[2];
    float* y = (float*)d_out;

    const int N = in_sizes[2];            // 4096
    const int K = in_sizes[1] / N;        // 4096
    const int M = in_sizes[0] / K;        // 8192

    uint8_t* ws = (uint8_t*)d_ws;
    int8_t* Wq = (int8_t*)ws;                                  // N*K   int8
    int8_t* Xq = (int8_t*)(ws + (size_t)N * K);                // M*K   int8
    uint8_t* p = ws + (size_t)N * K + (size_t)M * K;
    p = (uint8_t*)(((uintptr_t)p + 255) & ~(uintptr_t)255);
    float* rscale = (float*)p;  p += (size_t)N * sizeof(float);
    int*   rsum   = (int*)p;    p += (size_t)N * sizeof(int);
    float* cscale = (float*)p;  p += (size_t)M * sizeof(float);
    int*   azp    = (int*)p;    p += (size_t)M * sizeof(int);

    static int lds_cfg = 0;
    if (!lds_cfg) {
        (void)hipFuncSetAttribute((const void*)gemm_i8_kernel,
                                  hipFuncAttributeMaxDynamicSharedMemorySize, 131072);
        lds_cfg = 1;
    }

    wquant_kernel<<<N / 4, 256, 0, stream>>>(w, Wq, rscale, rsum, K);
    aquant_kernel<<<M / 4, 256, 0, stream>>>(x, Xq, cscale, azp, K);

    dim3 grid(M / 256, N / 256);
    gemm_i8_kernel<<<grid, 512, 131072, stream>>>(Xq, Wq, y, cscale, azp,
                                                  rscale, rsum, bias, M, N, K);
}

// Round 4
// 405.826 us; speedup vs baseline: 1.2386x; 1.0040x over previous
//
#include <hip/hip_runtime.h>
#include <stdint.h>
#include <stddef.h>

typedef __attribute__((ext_vector_type(4))) int i32x4;

// ---------------- async global -> LDS (16B per lane) ----------------
__device__ __forceinline__ void gload_lds16(const void* g, void* l) {
    __builtin_amdgcn_global_load_lds(
        (const __attribute__((address_space(1))) void*)g,
        (__attribute__((address_space(3))) void*)l,
        16, 0, 0);
}

// ---------------- wave-wide butterfly reductions (all lanes get result) ----------------
__device__ __forceinline__ float waveAllMaxF(float v) {
#pragma unroll
    for (int m = 32; m > 0; m >>= 1) v = fmaxf(v, __shfl_xor(v, m, 64));
    return v;
}
__device__ __forceinline__ float waveAllMinF(float v) {
#pragma unroll
    for (int m = 32; m > 0; m >>= 1) v = fminf(v, __shfl_xor(v, m, 64));
    return v;
}
__device__ __forceinline__ int waveAllSumI(int v) {
#pragma unroll
    for (int m = 32; m > 0; m >>= 1) v += __shfl_xor(v, m, 64);
    return v;
}

// ---------------- weight quantization: row-wise symmetric int8 ----------------
// ONE WAVE per row, row register-resident, single pass, no LDS/barriers.
__global__ void __launch_bounds__(256) wquant_kernel(
    const float* __restrict__ W, int8_t* __restrict__ Wq,
    float* __restrict__ rscale, int* __restrict__ rsum, int K) {
    const int n = blockIdx.x * 4 + (threadIdx.x >> 6);
    const int lane = threadIdx.x & 63;
    const float4* row = (const float4*)(W + (size_t)n * K);
    int* out = (int*)(Wq + (size_t)n * K);

    if (K == 4096) {
        float4 v[16];
#pragma unroll
        for (int j = 0; j < 16; ++j) v[j] = row[lane + (j << 6)];

        float amax = 0.f;
#pragma unroll
        for (int j = 0; j < 16; ++j) {
            amax = fmaxf(amax, fmaxf(fmaxf(fabsf(v[j].x), fabsf(v[j].y)),
                                     fmaxf(fabsf(v[j].z), fabsf(v[j].w))));
        }
        amax = waveAllMaxF(amax);
        const float scale = (amax > 0.f) ? (amax / 127.0f) : 1.0f;

        int lsum = 0;
#pragma unroll
        for (int j = 0; j < 16; ++j) {
            int q0 = (int)fminf(fmaxf(rintf(v[j].x / scale), -127.f), 127.f);
            int q1 = (int)fminf(fmaxf(rintf(v[j].y / scale), -127.f), 127.f);
            int q2 = (int)fminf(fmaxf(rintf(v[j].z / scale), -127.f), 127.f);
            int q3 = (int)fminf(fmaxf(rintf(v[j].w / scale), -127.f), 127.f);
            lsum += q0 + q1 + q2 + q3;
            out[lane + (j << 6)] =
                (q0 & 255) | ((q1 & 255) << 8) | ((q2 & 255) << 16) | ((q3 & 255) << 24);
        }
        lsum = waveAllSumI(lsum);
        if (lane == 0) { rsum[n] = lsum; rscale[n] = scale; }
    } else {
        const int K4 = K >> 2;
        float amax = 0.f;
        for (int i = lane; i < K4; i += 64) {
            float4 f = row[i];
            amax = fmaxf(amax, fmaxf(fmaxf(fabsf(f.x), fabsf(f.y)),
                                     fmaxf(fabsf(f.z), fabsf(f.w))));
        }
        amax = waveAllMaxF(amax);
        const float scale = (amax > 0.f) ? (amax / 127.0f) : 1.0f;
        int lsum = 0;
        for (int i = lane; i < K4; i += 64) {
            float4 f = row[i];
            int q0 = (int)fminf(fmaxf(rintf(f.x / scale), -127.f), 127.f);
            int q1 = (int)fminf(fmaxf(rintf(f.y / scale), -127.f), 127.f);
            int q2 = (int)fminf(fmaxf(rintf(f.z / scale), -127.f), 127.f);
            int q3 = (int)fminf(fmaxf(rintf(f.w / scale), -127.f), 127.f);
            lsum += q0 + q1 + q2 + q3;
            out[i] = (q0 & 255) | ((q1 & 255) << 8) | ((q2 & 255) << 16) | ((q3 & 255) << 24);
        }
        lsum = waveAllSumI(lsum);
        if (lane == 0) { rsum[n] = lsum; rscale[n] = scale; }
    }
}

// ---------------- activation quantization: per-token asymmetric uint8 ----------------
__global__ void __launch_bounds__(256) aquant_kernel(
    const float* __restrict__ X, int8_t* __restrict__ Xq,
    float* __restrict__ cscale, int* __restrict__ azp, int K) {
    const int m = blockIdx.x * 4 + (threadIdx.x >> 6);
    const int lane = threadIdx.x & 63;
    const float4* row = (const float4*)(X + (size_t)m * K);
    int* out = (int*)(Xq + (size_t)m * K);

    if (K == 4096) {
        float4 v[16];
#pragma unroll
        for (int j = 0; j < 16; ++j) v[j] = row[lane + (j << 6)];

        float vmin = 3.402823466e38f, vmax = -3.402823466e38f;
#pragma unroll
        for (int j = 0; j < 16; ++j) {
            vmin = fminf(vmin, fminf(fminf(v[j].x, v[j].y), fminf(v[j].z, v[j].w)));
            vmax = fmaxf(vmax, fmaxf(fmaxf(v[j].x, v[j].y), fmaxf(v[j].z, v[j].w)));
        }
        vmin = waveAllMinF(vmin);
        vmax = waveAllMaxF(vmax);

        const float rng = vmax - vmin;
        const float scale = (rng > 0.f) ? (rng / 255.0f) : 1.0f;
        const float zp = rintf(-vmin / scale);

#pragma unroll
        for (int j = 0; j < 16; ++j) {
            int q0 = (int)fminf(fmaxf(rintf(v[j].x / scale) + zp, 0.f), 255.f) - 128;
            int q1 = (int)fminf(fmaxf(rintf(v[j].y / scale) + zp, 0.f), 255.f) - 128;
            int q2 = (int)fminf(fmaxf(rintf(v[j].z / scale) + zp, 0.f), 255.f) - 128;
            int q3 = (int)fminf(fmaxf(rintf(v[j].w / scale) + zp, 0.f), 255.f) - 128;
            out[lane + (j << 6)] =
                (q0 & 255) | ((q1 & 255) << 8) | ((q2 & 255) << 16) | ((q3 & 255) << 24);
        }
        if (lane == 0) { cscale[m] = scale; azp[m] = 128 - (int)zp; }
    } else {
        const int K4 = K >> 2;
        float vmin = 3.402823466e38f, vmax = -3.402823466e38f;
        for (int i = lane; i < K4; i += 64) {
            float4 f = row[i];
            vmin = fminf(vmin, fminf(fminf(f.x, f.y), fminf(f.z, f.w)));
            vmax = fmaxf(vmax, fmaxf(fmaxf(f.x, f.y), fmaxf(f.z, f.w)));
        }
        vmin = waveAllMinF(vmin);
        vmax = waveAllMaxF(vmax);
        const float rng = vmax - vmin;
        const float scale = (rng > 0.f) ? (rng / 255.0f) : 1.0f;
        const float zp = rintf(-vmin / scale);
        for (int i = lane; i < K4; i += 64) {
            float4 f = row[i];
            int q0 = (int)fminf(fmaxf(rintf(f.x / scale) + zp, 0.f), 255.f) - 128;
            int q1 = (int)fminf(fmaxf(rintf(f.y / scale) + zp, 0.f), 255.f) - 128;
            int q2 = (int)fminf(fmaxf(rintf(f.z / scale) + zp, 0.f), 255.f) - 128;
            int q3 = (int)fminf(fmaxf(rintf(f.w / scale) + zp, 0.f), 255.f) - 128;
            out[i] = (q0 & 255) | ((q1 & 255) << 8) | ((q2 & 255) << 16) | ((q3 & 255) << 24);
        }
        if (lane == 0) { cscale[m] = scale; azp[m] = 128 - (int)zp; }
    }
}

// ---------------- int8 GEMM: 256x256 tile, 8 waves, 8-phase counted-vmcnt schedule ----------------
// A: [M,K] i8 (Xq), B: [N,K] i8 (Wq).
// Y[m,n] = (dot_i8(A[m],B[n]) + azp[m]*rsum[n]) * cs[m]*rs[n] + bias[n]
//
// Geometry: BM=BN=256, BK=128B, 512 thr = 8 waves (2M x 4N), per-wave 128x64 ->
// acc[8][4], XOR-swizzled LDS (0 bank conflicts verified in round 2), 2x64KB double
// buffer, XCD-bijective block swizzle.
//
// T3+T4+T5 schedule. Each K-tile = 4 phases {ds_read frags | issue 2 stage stripes |
// sched_barrier+s_barrier | lgkmcnt(0) | setprio(1) 16xMFMA setprio(0) | barrier}.
// Next tile's 8 stripes issued B0B1 | B2B3 | A0A2 | A1A3 across the phases.
// Counted waits (per-wave ledger): mid-tile vmcnt(4) retires exactly {A1,A3 of this
// tile} (in-flight then: those 2 + next tile's 4 B-loads = 6); boundary vmcnt(2)
// retires next tile's {B0..B3, A0, A2}, leaving {A1,A3} in flight. Never vmcnt(0)
// in steady state. All barriers/waits are wave-uniform (conditions depend only on t).
__global__ void __launch_bounds__(512, 2) gemm_i8_kernel(
    const int8_t* __restrict__ A, const int8_t* __restrict__ B,
    float* __restrict__ Y,
    const float* __restrict__ cs, const int* __restrict__ azp,
    const float* __restrict__ rs, const int* __restrict__ rsum,
    const float* __restrict__ bias, int M, int N, int K) {
    extern __shared__ int8_t smem[];  // [2][A:32KB | B:32KB]

    const int tid = threadIdx.x;
    const int lane = tid & 63;
    const int wave = tid >> 6;
    const int wm = wave >> 2;   // 0..1  (M side, 128 rows each)
    const int wn = wave & 3;    // 0..3  (N side, 64 cols each)
    const int quad = lane >> 4; // 0..3
    const int lr = lane & 15;

    // ---- XCD-aware bijective block swizzle ----
    const int nwg = gridDim.x * gridDim.y;
    int wid = blockIdx.y * gridDim.x + blockIdx.x;
    if ((nwg & 7) == 0) wid = (wid & 7) * (nwg >> 3) + (wid >> 3);
    const int bm = (wid % gridDim.x) * 256;
    const int bn = (wid / gridDim.x) * 256;

    const int8_t* Ag = A + (size_t)bm * K;
    const int8_t* Bg = B + (size_t)bn * K;

    // ---- staging map: 64-row stripes; thread covers row sr of each stripe, 16B slot sc
    //      (lane-linear LDS dest; swizzle carried on the global source column) ----
    const int sr = tid >> 3;
    const int sc = tid & 7;
    const int csrc = (sc ^ (sr & 7)) << 4;

#define STAGE_A(dst, k0, s) { const int r_ = ((s) << 6) + sr; \
    gload_lds16(Ag + (size_t)r_ * K + ((k0) + csrc), (dst) + r_ * 128 + (sc << 4)); }
#define STAGE_B(dst, k0, s) { const int r_ = ((s) << 6) + sr; \
    gload_lds16(Bg + (size_t)r_ * K + ((k0) + csrc), (dst) + 32768 + r_ * 128 + (sc << 4)); }

    i32x4 acc[8][4] = {};
    const int NT = K >> 7;  // K-tiles of 128 bytes

    // ---- prologue: stage tile 0 into buf0; order B0..B3, A0, A2, A1, A3 ----
    {
        int8_t* d = smem;
        STAGE_B(d, 0, 0) STAGE_B(d, 0, 1) STAGE_B(d, 0, 2) STAGE_B(d, 0, 3)
        STAGE_A(d, 0, 0) STAGE_A(d, 0, 2) STAGE_A(d, 0, 1) STAGE_A(d, 0, 3)
    }
    asm volatile("s_waitcnt vmcnt(2)" ::: "memory");  // A1,A3 may lag (read in phase 2)
    __builtin_amdgcn_sched_barrier(0);
    __builtin_amdgcn_s_barrier();

    // ---- fragment read addressing (identical layout to verified 2-phase version) ----
    const int axor = lr & 7;
    const int off_k0 = ((quad ^ axor) << 4);        // kk=0 slot byte offset
    const int off_k1 = (((4 | quad) ^ axor) << 4);  // kk=1 slot byte offset
    const int aBase = (wm * 128 + lr) * 128;        // + ih*8192 + i*2048
    const int bBase = (wn * 64 + lr) * 128;         // + j*2048

    for (int t = 0; t < NT; ++t) {
        const int8_t* Ab = smem + ((t & 1) << 16);
        const int8_t* Bb = Ab + 32768;
        int8_t* nb = smem + (((t + 1) & 1) << 16);
        const int k0n = (t + 1) << 7;
        const bool pf = (t + 1) < NT;

        i32x4 af[4], bf0[4], bf1[4];

        // ========== phase 0: (ih=0, kk=0) ==========
#pragma unroll
        for (int j = 0; j < 4; ++j) bf0[j] = *(const i32x4*)&Bb[bBase + j * 2048 + off_k0];
#pragma unroll
        for (int i = 0; i < 4; ++i) af[i] = *(const i32x4*)&Ab[aBase + i * 2048 + off_k0];
        if (pf) { STAGE_B(nb, k0n, 0) STAGE_B(nb, k0n, 1) }
        __builtin_amdgcn_sched_barrier(0);
        __builtin_amdgcn_s_barrier();
        asm volatile("s_waitcnt lgkmcnt(0)" ::: "memory");
        __builtin_amdgcn_sched_barrier(0);
        __builtin_amdgcn_s_setprio(1);
#pragma unroll
        for (int i = 0; i < 4; ++i)
#pragma unroll
            for (int j = 0; j < 4; ++j)
                acc[i][j] = __builtin_amdgcn_mfma_i32_16x16x64_i8(af[i], bf0[j], acc[i][j], 0, 0, 0);
        __builtin_amdgcn_s_setprio(0);
        __builtin_amdgcn_sched_barrier(0);
        __builtin_amdgcn_s_barrier();

        // ========== phase 1: (ih=0, kk=1) ==========
#pragma unroll
        for (int j = 0; j < 4; ++j) bf1[j] = *(const i32x4*)&Bb[bBase + j * 2048 + off_k1];
#pragma unroll
        for (int i = 0; i < 4; ++i) af[i] = *(const i32x4*)&Ab[aBase + i * 2048 + off_k1];
        if (pf) { STAGE_B(nb, k0n, 2) STAGE_B(nb, k0n, 3) }
        __builtin_amdgcn_sched_barrier(0);
        __builtin_amdgcn_s_barrier();
        asm volatile("s_waitcnt lgkmcnt(0)" ::: "memory");
        __builtin_amdgcn_sched_barrier(0);
        __builtin_amdgcn_s_setprio(1);
#pragma unroll
        for (int i = 0; i < 4; ++i)
#pragma unroll
            for (int j = 0; j < 4; ++j)
                acc[i][j] = __builtin_amdgcn_mfma_i32_16x16x64_i8(af[i], bf1[j], acc[i][j], 0, 0, 0);
        __builtin_amdgcn_s_setprio(0);
        __builtin_amdgcn_sched_barrier(0);
        // mid-tile wait: THIS tile's A1,A3 must be resident for phases 2-3.
        if (pf) { asm volatile("s_waitcnt vmcnt(4)" ::: "memory"); }
        else    { asm volatile("s_waitcnt vmcnt(0)" ::: "memory"); }
        __builtin_amdgcn_s_barrier();

        // ========== phase 2: (ih=1, kk=0) ==========
#pragma unroll
        for (int i = 0; i < 4; ++i) af[i] = *(const i32x4*)&Ab[aBase + 8192 + i * 2048 + off_k0];
        if (pf) { STAGE_A(nb, k0n, 0) STAGE_A(nb, k0n, 2) }
        __builtin_amdgcn_sched_barrier(0);
        __builtin_amdgcn_s_barrier();
        asm volatile("s_waitcnt lgkmcnt(0)" ::: "memory");
        __builtin_amdgcn_sched_barrier(0);
        __builtin_amdgcn_s_setprio(1);
#pragma unroll
        for (int i = 0; i < 4; ++i)
#pragma unroll
            for (int j = 0; j < 4; ++j)
                acc[4 + i][j] = __builtin_amdgcn_mfma_i32_16x16x64_i8(af[i], bf0[j], acc[4 + i][j], 0, 0, 0);
        __builtin_amdgcn_s_setprio(0);
        __builtin_amdgcn_sched_barrier(0);
        __builtin_amdgcn_s_barrier();

        // ========== phase 3: (ih=1, kk=1) ==========
#pragma unroll
        for (int i = 0; i < 4; ++i) af[i] = *(const i32x4*)&Ab[aBase + 8192 + i * 2048 + off_k1];
        if (pf) { STAGE_A(nb, k0n, 1) STAGE_A(nb, k0n, 3) }
        __builtin_amdgcn_sched_barrier(0);
        __builtin_amdgcn_s_barrier();
        asm volatile("s_waitcnt lgkmcnt(0)" ::: "memory");
        __builtin_amdgcn_sched_barrier(0);
        __builtin_amdgcn_s_setprio(1);
#pragma unroll
        for (int i = 0; i < 4; ++i)
#pragma unroll
            for (int j = 0; j < 4; ++j)
                acc[4 + i][j] = __builtin_amdgcn_mfma_i32_16x16x64_i8(af[i], bf1[j], acc[4 + i][j], 0, 0, 0);
        __builtin_amdgcn_s_setprio(0);
        __builtin_amdgcn_sched_barrier(0);
        // tile boundary: next tile's B0..B3,A0,A2 must be resident; A1,A3 stay in flight.
        if (pf) { asm volatile("s_waitcnt vmcnt(2)" ::: "memory"); }
        __builtin_amdgcn_s_barrier();
    }
#undef STAGE_A
#undef STAGE_B

    // epilogue: C/D layout col = lane&15 (n side), row = quad*4 + reg (m side)
#pragma unroll
    for (int i = 0; i < 8; ++i) {
        const int mb = bm + wm * 128 + i * 16 + quad * 4;
#pragma unroll
        for (int r = 0; r < 4; ++r) {
            const int m = mb + r;
            const float csm = cs[m];
            const int az = azp[m];
            float* yrow = Y + (size_t)m * N;
#pragma unroll
            for (int j = 0; j < 4; ++j) {
                const int n = bn + wn * 64 + j * 16 + lr;
                const int tot = acc[i][j][r] + az * rsum[n];
                yrow[n] = fmaf((float)tot, csm * rs[n], bias[n]);
            }
        }
    }
}

// ---------------- launch ----------------
extern "C" void kernel_launch(void* const* d_in, const int* in_sizes, int n_in,
                              void* d_out, int out_size, void* d_ws, size_t ws_size,
                              hipStream_t stream) {
    const float* x = (const float*)d_in[0];
    const float* w = (const float*)d_in[1];
    const float* bias = (const float*)d_in[2];
    float* y = (float*)d_out;

    const int N = in_sizes[2];            // 4096
    const int K = in_sizes[1] / N;        // 4096
    const int M = in_sizes[0] / K;        // 8192

    uint8_t* ws = (uint8_t*)d_ws;
    int8_t* Wq = (int8_t*)ws;                                  // N*K   int8
    int8_t* Xq = (int8_t*)(ws + (size_t)N * K);                // M*K   int8
    uint8_t* p = ws + (size_t)N * K + (size_t)M * K;
    p = (uint8_t*)(((uintptr_t)p + 255) & ~(uintptr_t)255);
    float* rscale = (float*)p;  p += (size_t)N * sizeof(float);
    int*   rsum   = (int*)p;    p += (size_t)N * sizeof(int);
    float* cscale = (float*)p;  p += (size_t)M * sizeof(float);
    int*   azp    = (int*)p;    p += (size_t)M * sizeof(int);

    static int lds_cfg = 0;
    if (!lds_cfg) {
        (void)hipFuncSetAttribute((const void*)gemm_i8_kernel,
                                  hipFuncAttributeMaxDynamicSharedMemorySize, 131072);
        lds_cfg = 1;
    }

    wquant_kernel<<<N / 4, 256, 0, stream>>>(w, Wq, rscale, rsum, K);
    aquant_kernel<<<M / 4, 256, 0, stream>>>(x, Xq, cscale, azp, K);

    dim3 grid(M / 256, N / 256);
    gemm_i8_kernel<<<grid, 512, 131072, stream>>>(Xq, Wq, y, cscale, azp,
                                                  rscale, rsum, bias, M, N, K);
}